// Round 3
// baseline (572.235 us; speedup 1.0000x reference)
//
#include <hip/hip_runtime.h>
#include <cstdint>

#define B_SZ 16
#define T_SZ 2048
#define H_SZ 1024
#define K_SZ 2048              // 2H
#define M_SZ (B_SZ * T_SZ)     // 32768

// fallback-path tile params
#define BM 128
#define BN 128
#define BK 64
#define LDK 72
#define KTILES (K_SZ / BK)     // 32

// fused-path tile params
#define FBM 64                 // rows per block
#define FBK 32                 // K per step
#define NSTEPS (K_SZ / FBK)    // 64

typedef _Float16 half8_t __attribute__((ext_vector_type(8)));
typedef _Float16 half4_t __attribute__((ext_vector_type(4)));
typedef float float4_t __attribute__((ext_vector_type(4)));

__device__ __forceinline__ void glds16(const _Float16* g, _Float16* l) {
    __builtin_amdgcn_global_load_lds(
        (const __attribute__((address_space(1))) void*)g,
        (__attribute__((address_space(3))) void*)l, 16, 0, 0);
}

// ---------------------------------------------------------------------------
// Kernel 0b: W2 -> fp16, packed FRAGMENT-MAJOR:
//   chunk(nblk, kblk) = 1 KB contiguous: lane = quad*16+m16 holds 8 halves
//   Bp[((nblk*64 + kblk)*64 + quad*16 + m16)*8 + j] = W[n][1024+k]
//   n = nblk*16 + m16, k = kblk*32 + quad*8 + j.  (4 MB total, L2-resident)
// ---------------------------------------------------------------------------
__global__ __launch_bounds__(256) void cvt_w2_kernel(
    const float* __restrict__ W, _Float16* __restrict__ dst) {
    int idx8 = blockIdx.x * 256 + threadIdx.x;  // [0, 262144)
    int n = idx8 >> 8, k = (idx8 & 255) * 8;
    const float* src = W + (size_t)n * 3072 + H_SZ + k;
    float4_t a = *(const float4_t*)(src);
    float4_t b = *(const float4_t*)(src + 4);
    half8_t h;
    h[0] = (_Float16)a[0]; h[1] = (_Float16)a[1];
    h[2] = (_Float16)a[2]; h[3] = (_Float16)a[3];
    h[4] = (_Float16)b[0]; h[5] = (_Float16)b[1];
    h[6] = (_Float16)b[2]; h[7] = (_Float16)b[3];
    int nblk = n >> 4, m16 = n & 15;
    int kblk = k >> 5, quad = (k >> 3) & 3;
    size_t di = (((size_t)nblk * 64 + kblk) * 64 + quad * 16 + m16) * 8;
    *(half8_t*)(dst + di) = h;
}

// ---------------------------------------------------------------------------
// Kernel 1: hpart[b][h] = bias[h] + dot(hidden[b, :], W[h, 0:1024])
// ---------------------------------------------------------------------------
__global__ __launch_bounds__(256) void hpart_kernel(
    const float* __restrict__ hidden, const float* __restrict__ W,
    const float* __restrict__ bias, float* __restrict__ hpart) {
    int wave = (blockIdx.x * 256 + threadIdx.x) >> 6;  // [0, 16384)
    int lane = threadIdx.x & 63;
    int b = wave >> 10;
    int h = wave & 1023;
    const float* wrow = W + (size_t)h * 3072;
    const float* hrow = hidden + b * H_SZ;
    int k0 = lane * 16;
    float acc = 0.f;
#pragma unroll
    for (int j = 0; j < 4; ++j) {
        float4_t wv = *(const float4_t*)(wrow + k0 + j * 4);
        float4_t hv = *(const float4_t*)(hrow + k0 + j * 4);
        acc += wv[0] * hv[0] + wv[1] * hv[1] + wv[2] * hv[2] + wv[3] * hv[3];
    }
#pragma unroll
    for (int off = 32; off >= 1; off >>= 1) acc += __shfl_xor(acc, off, 64);
    if (lane == 0) hpart[b * H_SZ + h] = acc + bias[h];
}

// ---------------------------------------------------------------------------
// Kernel 2 (fused v2): 512 threads = 8 waves. Block = 64 rows x full N=1024.
//   Wave tile 64x128 (TM=4 m-subtiles, TN=8 n-subtiles), acc 4x8 float4.
//   A (enc fp32): nontemporal global->reg, cvt fp16, swizzled LDS [64][32],
//     double-buffered (2x4 KB). Key (row>>1)&3 on 16B granules.
//   B: global_load_lds (16 B) from packed table into double-buffered LDS
//     (2x64 KB), fragment-major; each wave stages+consumes its own 8 chunks.
//     Issued at loop top for kt+1; drained by end-of-step barrier after the
//     ~1240-cy MFMA phase (L2 latency fully hidden).
//   Epilogue: tanh(acc+hp)*v, m16 shuffle reduce, cross-wave LDS reduce
//     (sred aliases A buffers), final scores -> (B,T).
// ---------------------------------------------------------------------------
__global__ __launch_bounds__(512, 2) void fused2_attn_kernel(
    const float* __restrict__ enc, const _Float16* __restrict__ Bp,
    const float* __restrict__ hpart, const float* __restrict__ v,
    float* __restrict__ scores) {
    __shared__ __align__(16) _Float16 Als[2][FBM * FBK];   // 2 x 4 KB
    __shared__ __align__(16) _Float16 Bls[2][64 * 512];    // 2 x 64 KB

    const int tid = threadIdx.x;
    const int lane = tid & 63;
    const int w = tid >> 6;          // 0..7 == wn (n-group of 128 cols)
    const int m16 = lane & 15, quad = lane >> 4;

    const int blockM = blockIdx.x;   // 0..511
    const int batch = blockM >> 5;   // 64 rows/block, 32 blocks/batch

    // ---- A staging addressing (fp32 global -> swizzled LDS fp16) ----
    const int arow = tid >> 3;       // 0..63
    const int ac8 = tid & 7;         // float4 group within the 32-float row
    const float* Ap = enc + (size_t)(blockM * FBM + arow) * K_SZ + ac8 * 4;
    // write 8 B: granule g=ac8>>1 XOR-keyed by (row>>1)&3
    const int awbyte = arow * 64 +
        ((((ac8 >> 1) ^ ((arow >> 1) & 3)) << 4) | ((ac8 & 1) << 3));

    // ---- A frag read offsets (same XOR key on read) ----
    int afb[4];
#pragma unroll
    for (int tm = 0; tm < 4; ++tm) {
        int r = tm * 16 + m16;
        afb[tm] = r * 64 + ((quad ^ ((r >> 1) & 3)) << 4);
    }

    // ---- B global base: wave w stages chunks nblk = w*8+i at kblk = kt ----
    // halves offset: ((w*8+i)*64 + kt)*512 + lane*8
    const _Float16* Bg = Bp + ((size_t)(w * 8) * 64) * 512 + lane * 8;

    float4_t acc[4][8];
#pragma unroll
    for (int i = 0; i < 4; ++i)
#pragma unroll
        for (int j = 0; j < 8; ++j) acc[i][j] = (float4_t){0.f, 0.f, 0.f, 0.f};

    // ---- prologue: stage K-step 0 into buffer 0 ----
    {
        float4_t av = __builtin_nontemporal_load((const float4_t*)Ap);
#pragma unroll
        for (int i = 0; i < 8; ++i)
            glds16(Bg + (size_t)i * (64 * 512), &Bls[0][(w * 8 + i) * 512]);
        half4_t h;
        h[0] = (_Float16)av[0]; h[1] = (_Float16)av[1];
        h[2] = (_Float16)av[2]; h[3] = (_Float16)av[3];
        *(half4_t*)((char*)Als[0] + awbyte) = h;
    }
    __syncthreads();

    int cur = 0;
    for (int kt = 0; kt < NSTEPS; ++kt) {
        const bool pre = (kt + 1 < NSTEPS);
        float4_t av;
        if (pre) {
            av = __builtin_nontemporal_load(
                (const float4_t*)(Ap + (size_t)(kt + 1) * FBK));
#pragma unroll
            for (int i = 0; i < 8; ++i)
                glds16(Bg + (size_t)i * (64 * 512) + (size_t)(kt + 1) * 512,
                       &Bls[cur ^ 1][(w * 8 + i) * 512]);
        }
        // ---- frag reads from current buffers ----
        half8_t af[4], bf[8];
#pragma unroll
        for (int tm = 0; tm < 4; ++tm)
            af[tm] = *(const half8_t*)((const char*)Als[cur] + afb[tm]);
#pragma unroll
        for (int tn = 0; tn < 8; ++tn)
            bf[tn] = *(const half8_t*)&Bls[cur][(w * 8 + tn) * 512 + lane * 8];

        __builtin_amdgcn_s_setprio(1);
#pragma unroll
        for (int tm = 0; tm < 4; ++tm)
#pragma unroll
            for (int tn = 0; tn < 8; ++tn)
                acc[tm][tn] = __builtin_amdgcn_mfma_f32_16x16x32_f16(
                    af[tm], bf[tn], acc[tm][tn], 0, 0, 0);
        __builtin_amdgcn_s_setprio(0);

        if (pre) {
            half4_t h;
            h[0] = (_Float16)av[0]; h[1] = (_Float16)av[1];
            h[2] = (_Float16)av[2]; h[3] = (_Float16)av[3];
            *(half4_t*)((char*)Als[cur ^ 1] + awbyte) = h;
        }
        __syncthreads();
        cur ^= 1;
    }

    // ---- epilogue: tanh + v-dot, reduce over N ----
    float* sred = (float*)Als;  // [8][64], aliases A buffers (free after loop)

    float hpv[8], vv[8];
#pragma unroll
    for (int tn = 0; tn < 8; ++tn) {
        int col = w * 128 + tn * 16 + m16;
        hpv[tn] = hpart[batch * H_SZ + col];
        vv[tn] = v[col];
    }

#pragma unroll
    for (int tm = 0; tm < 4; ++tm) {
        float s0 = 0.f, s1 = 0.f, s2 = 0.f, s3 = 0.f;
#pragma unroll
        for (int tn = 0; tn < 8; ++tn) {
            s0 += tanhf(acc[tm][tn][0] + hpv[tn]) * vv[tn];
            s1 += tanhf(acc[tm][tn][1] + hpv[tn]) * vv[tn];
            s2 += tanhf(acc[tm][tn][2] + hpv[tn]) * vv[tn];
            s3 += tanhf(acc[tm][tn][3] + hpv[tn]) * vv[tn];
        }
#pragma unroll
        for (int off = 1; off < 16; off <<= 1) {
            s0 += __shfl_xor(s0, off, 64);
            s1 += __shfl_xor(s1, off, 64);
            s2 += __shfl_xor(s2, off, 64);
            s3 += __shfl_xor(s3, off, 64);
        }
        if (m16 == 0) {
            int rl = tm * 16 + quad * 4;
            sred[w * 64 + rl + 0] = s0;
            sred[w * 64 + rl + 1] = s1;
            sred[w * 64 + rl + 2] = s2;
            sred[w * 64 + rl + 3] = s3;
        }
    }
    __syncthreads();
    if (tid < FBM) {
        float t = 0.f;
#pragma unroll
        for (int i = 0; i < 8; ++i) t += sred[i * 64 + tid];
        scores[(size_t)blockM * FBM + tid] = t;
    }
}

// ---------------------------------------------------------------------------
// Kernel 3 (fast path): per-batch softmax over T=2048, single score slice.
// ---------------------------------------------------------------------------
__global__ __launch_bounds__(256) void softmax1_kernel(
    const float* __restrict__ scores, float* __restrict__ out) {
    __shared__ float red[256];
    const int b = blockIdx.x;
    const int tid = threadIdx.x;
    float sc[8];
    float mymax = -1e30f;
#pragma unroll
    for (int i = 0; i < 8; ++i) {
        float s = scores[b * T_SZ + i * 256 + tid];
        sc[i] = s;
        mymax = fmaxf(mymax, s);
    }
    red[tid] = mymax;
    __syncthreads();
    for (int off = 128; off >= 1; off >>= 1) {
        if (tid < off) red[tid] = fmaxf(red[tid], red[tid + off]);
        __syncthreads();
    }
    float mx = red[0];
    __syncthreads();
    float mysum = 0.f;
#pragma unroll
    for (int i = 0; i < 8; ++i) {
        sc[i] = expf(sc[i] - mx);
        mysum += sc[i];
    }
    red[tid] = mysum;
    __syncthreads();
    for (int off = 128; off >= 1; off >>= 1) {
        if (tid < off) red[tid] += red[tid + off];
        __syncthreads();
    }
    float inv = 1.0f / red[0];
#pragma unroll
    for (int i = 0; i < 8; ++i) out[b * T_SZ + i * 256 + tid] = sc[i] * inv;
}

// ---------------------------------------------------------------------------
// Fallback GEMM: fp32 loads with in-flight cvt (if ws too small)
// ---------------------------------------------------------------------------
__global__ __launch_bounds__(256, 2) void attn_gemm_kernel(
    const float* __restrict__ enc, const float* __restrict__ W,
    const float* __restrict__ hpart, const float* __restrict__ v,
    float* __restrict__ partial) {
    __shared__ _Float16 Afs[BM * LDK];
    __shared__ _Float16 Bfs[BN * LDK];
    __shared__ float hp_s[BN];
    __shared__ float v_s[BN];

    const int bidx = blockIdx.x;
    const int blockN = bidx & 7;
    const int blockM = bidx >> 3;
    const int tid = threadIdx.x;
    const int lane = tid & 63;
    const int w = tid >> 6;
    const int wm = w & 1, wn = w >> 1;
    const int m16 = lane & 15, quad = lane >> 4;

    const int n0 = blockN * BN;
    const int batch = blockM >> 4;

    if (tid < BN) {
        hp_s[tid] = hpart[batch * H_SZ + n0 + tid];
        v_s[tid] = v[n0 + tid];
    }

    float4_t acc[4][4];
#pragma unroll
    for (int i = 0; i < 4; ++i)
#pragma unroll
        for (int j = 0; j < 4; ++j) acc[i][j] = (float4_t){0.f, 0.f, 0.f, 0.f};

    const float* Abase = enc + (size_t)(blockM * BM) * K_SZ;
    const float* Bbase = W + (size_t)n0 * 3072 + H_SZ;

    for (int kt = 0; kt < KTILES; ++kt) {
        __syncthreads();
        const float* Asrc0 = Abase + kt * BK;
#pragma unroll
        for (int i = 0; i < 4; ++i) {
            int f8 = i * 256 + tid;
            int r = f8 >> 3, c8 = f8 & 7;
            const float* src = Asrc0 + (size_t)r * K_SZ + c8 * 8;
            float4_t lo = *(const float4_t*)(src);
            float4_t hi = *(const float4_t*)(src + 4);
            half8_t hv;
            hv[0] = (_Float16)lo[0]; hv[1] = (_Float16)lo[1];
            hv[2] = (_Float16)lo[2]; hv[3] = (_Float16)lo[3];
            hv[4] = (_Float16)hi[0]; hv[5] = (_Float16)hi[1];
            hv[6] = (_Float16)hi[2]; hv[7] = (_Float16)hi[3];
            *(half8_t*)&Afs[r * LDK + c8 * 8] = hv;
        }
        const float* Bsrc0 = Bbase + kt * BK;
#pragma unroll
        for (int i = 0; i < 4; ++i) {
            int f8 = i * 256 + tid;
            int r = f8 >> 3, c8 = f8 & 7;
            const float* src = Bsrc0 + (size_t)r * 3072 + c8 * 8;
            float4_t lo = *(const float4_t*)(src);
            float4_t hi = *(const float4_t*)(src + 4);
            half8_t hv;
            hv[0] = (_Float16)lo[0]; hv[1] = (_Float16)lo[1];
            hv[2] = (_Float16)lo[2]; hv[3] = (_Float16)lo[3];
            hv[4] = (_Float16)hi[0]; hv[5] = (_Float16)hi[1];
            hv[6] = (_Float16)hi[2]; hv[7] = (_Float16)hi[3];
            *(half8_t*)&Bfs[r * LDK + c8 * 8] = hv;
        }
        __syncthreads();
#pragma unroll
        for (int ks = 0; ks < 2; ++ks) {
            half8_t afrag[4], bfrag[4];
#pragma unroll
            for (int tm = 0; tm < 4; ++tm)
                afrag[tm] = *(const half8_t*)&Afs[(wm * 64 + tm * 16 + m16) * LDK + ks * 32 + quad * 8];
#pragma unroll
            for (int tn = 0; tn < 4; ++tn)
                bfrag[tn] = *(const half8_t*)&Bfs[(wn * 64 + tn * 16 + m16) * LDK + ks * 32 + quad * 8];
#pragma unroll
            for (int tm = 0; tm < 4; ++tm)
#pragma unroll
                for (int tn = 0; tn < 4; ++tn)
                    acc[tm][tn] = __builtin_amdgcn_mfma_f32_16x16x32_f16(
                        afrag[tm], bfrag[tn], acc[tm][tn], 0, 0, 0);
        }
    }

    const int slice = blockN * 2 + wn;
#pragma unroll
    for (int tm = 0; tm < 4; ++tm) {
        float s0 = 0.f, s1 = 0.f, s2 = 0.f, s3 = 0.f;
#pragma unroll
        for (int tn = 0; tn < 4; ++tn) {
            int nl = wn * 64 + tn * 16 + m16;
            float hpv = hp_s[nl];
            float vv = v_s[nl];
            s0 += tanhf(acc[tm][tn][0] + hpv) * vv;
            s1 += tanhf(acc[tm][tn][1] + hpv) * vv;
            s2 += tanhf(acc[tm][tn][2] + hpv) * vv;
            s3 += tanhf(acc[tm][tn][3] + hpv) * vv;
        }
#pragma unroll
        for (int off = 1; off < 16; off <<= 1) {
            s0 += __shfl_xor(s0, off, 64);
            s1 += __shfl_xor(s1, off, 64);
            s2 += __shfl_xor(s2, off, 64);
            s3 += __shfl_xor(s3, off, 64);
        }
        if (m16 == 0) {
            int gm = blockM * BM + wm * 64 + tm * 16 + quad * 4;
            float* dst = partial + (size_t)slice * M_SZ + gm;
            dst[0] = s0; dst[1] = s1; dst[2] = s2; dst[3] = s3;
        }
    }
}

// ---------------------------------------------------------------------------
// Fallback softmax: sums the 16 partial slices.
// ---------------------------------------------------------------------------
__global__ __launch_bounds__(256) void softmax_kernel(
    const float* __restrict__ partial, float* __restrict__ out) {
    __shared__ float red[256];
    const int b = blockIdx.x;
    const int tid = threadIdx.x;
    float sc[8];
    float mymax = -1e30f;
#pragma unroll
    for (int i = 0; i < 8; ++i) {
        int t = i * 256 + tid;
        float s = 0.f;
#pragma unroll
        for (int sl = 0; sl < 16; ++sl) s += partial[(size_t)sl * M_SZ + b * T_SZ + t];
        sc[i] = s;
        mymax = fmaxf(mymax, s);
    }
    red[tid] = mymax;
    __syncthreads();
    for (int off = 128; off >= 1; off >>= 1) {
        if (tid < off) red[tid] = fmaxf(red[tid], red[tid + off]);
        __syncthreads();
    }
    float mx = red[0];
    __syncthreads();
    float mysum = 0.f;
#pragma unroll
    for (int i = 0; i < 8; ++i) {
        sc[i] = expf(sc[i] - mx);
        mysum += sc[i];
    }
    red[tid] = mysum;
    __syncthreads();
    for (int off = 128; off >= 1; off >>= 1) {
        if (tid < off) red[tid] += red[tid + off];
        __syncthreads();
    }
    float inv = 1.0f / red[0];
#pragma unroll
    for (int i = 0; i < 8; ++i) out[b * T_SZ + i * 256 + tid] = sc[i] * inv;
}

// ---------------------------------------------------------------------------
extern "C" void kernel_launch(void* const* d_in, const int* in_sizes, int n_in,
                              void* d_out, int out_size, void* d_ws, size_t ws_size,
                              hipStream_t stream) {
    const float* hidden = (const float*)d_in[0];  // (16, 1024)
    const float* enc    = (const float*)d_in[1];  // (16, 2048, 2048)
    const float* W      = (const float*)d_in[2];  // (1024, 3072)
    const float* bias   = (const float*)d_in[3];  // (1024,)
    const float* v      = (const float*)d_in[4];  // (1024,)
    float* out = (float*)d_out;                   // (16, 1, 2048)

    // ws layout (fast): hpart 64 KB | scores 128 KB | w2h packed 4 MB
    float* hpart  = (float*)d_ws;
    float* scores = hpart + B_SZ * H_SZ;           // M_SZ floats
    _Float16* w2h = (_Float16*)(scores + M_SZ);
    const size_t need = (size_t)((char*)(w2h + (size_t)H_SZ * K_SZ) - (char*)d_ws);

    hipLaunchKernelGGL(hpart_kernel, dim3(4096), dim3(256), 0, stream,
                       hidden, W, bias, hpart);
    if (ws_size >= need) {
        hipLaunchKernelGGL(cvt_w2_kernel, dim3(1024), dim3(256), 0, stream, W, w2h);
        hipLaunchKernelGGL(fused2_attn_kernel, dim3(M_SZ / FBM), dim3(512), 0, stream,
                           enc, w2h, hpart, v, scores);
        hipLaunchKernelGGL(softmax1_kernel, dim3(B_SZ), dim3(256), 0, stream,
                           scores, out);
    } else {
        // fallback: ws layout: hpart | partial (16 slices, 2 MB)
        float* partial = scores;
        hipLaunchKernelGGL(attn_gemm_kernel, dim3(2048), dim3(256), 0, stream,
                           enc, W, hpart, v, partial);
        hipLaunchKernelGGL(softmax_kernel, dim3(B_SZ), dim3(256), 0, stream,
                           partial, out);
    }
}